// Round 2
// baseline (2408.628 us; speedup 1.0000x reference)
//
#include <hip/hip_runtime.h>
#include <cstdint>
#include <cstddef>

typedef unsigned short u16;
typedef __attribute__((ext_vector_type(8))) __bf16 bf16x8;
typedef __attribute__((ext_vector_type(4))) float f32x4;

// fp32 -> bf16 round-to-nearest-even (inputs are well-behaved, no NaN path)
__device__ __forceinline__ u16 f2bf(float f) {
  union { float f; unsigned u; } v; v.f = f;
  unsigned r = v.u + 0x7FFFu + ((v.u >> 16) & 1u);
  return (u16)(r >> 16);
}
__device__ __forceinline__ float bf2f(unsigned h) {
  union { unsigned u; float f; } v; v.u = h << 16;
  return v.f;
}

// ---------------------------------------------------------------- subdom loss
__global__ void init_loss_kernel(const float* __restrict__ c,
                                 const int* __restrict__ D,
                                 const int* __restrict__ K,
                                 float* __restrict__ out) {
  out[0] = -c[0] * (float)D[0] * (float)K[0];
}

__global__ void subdom_kernel(const float4* __restrict__ dm,
                              const float4* __restrict__ sl,
                              const float4* __restrict__ alpha4,
                              float* __restrict__ out, int n4, int k4mask) {
  const int stride = gridDim.x * blockDim.x;
  float s = 0.f;
  for (int i = blockIdx.x * blockDim.x + threadIdx.x; i < n4; i += stride) {
    float4 d = dm[i], l = sl[i], a = alpha4[i & k4mask];
    s += fmaxf(fmaf(a.x, l.x - d.x, 1.f), 0.f);
    s += fmaxf(fmaf(a.y, l.y - d.y, 1.f), 0.f);
    s += fmaxf(fmaf(a.z, l.z - d.z, 1.f), 0.f);
    s += fmaxf(fmaf(a.w, l.w - d.w, 1.f), 0.f);
  }
#pragma unroll
  for (int off = 32; off > 0; off >>= 1) s += __shfl_down(s, off, 64);
  __shared__ float red[4];
  const int lane = threadIdx.x & 63, wave = threadIdx.x >> 6;
  if (lane == 0) red[wave] = s;
  __syncthreads();
  if (threadIdx.x == 0) atomicAdd(out, red[0] + red[1] + red[2] + red[3]);
}

// ---------------------------------------------------------------- casts
__global__ void cast_f32_bf16_kernel(const float4* __restrict__ in,
                                     u16* __restrict__ out, int n4) {
  const int stride = gridDim.x * blockDim.x;
  for (int i = blockIdx.x * blockDim.x + threadIdx.x; i < n4; i += stride) {
    float4 v = in[i];
    uint2 p;
    p.x = (unsigned)f2bf(v.x) | ((unsigned)f2bf(v.y) << 16);
    p.y = (unsigned)f2bf(v.z) | ((unsigned)f2bf(v.w) << 16);
    ((uint2*)out)[i] = p;
  }
}

// in: [K,N] fp32 row-major  ->  out: [N,K] bf16 row-major
__global__ void transpose_cast_kernel(const float* __restrict__ in,
                                      u16* __restrict__ out, int K, int N) {
  __shared__ float tile[32][33];
  const int bx = blockIdx.x * 32;  // N
  const int by = blockIdx.y * 32;  // K
  const int tx = threadIdx.x, ty = threadIdx.y;
#pragma unroll
  for (int i = ty; i < 32; i += 8)
    tile[i][tx] = in[(size_t)(by + i) * N + bx + tx];
  __syncthreads();
#pragma unroll
  for (int i = ty; i < 32; i += 8)
    out[(size_t)(bx + i) * K + by + tx] = f2bf(tile[tx][i]);
}

// ---------------------------------------------------------------- GEMM (m97 structure)
#define BM 128
#define BN 128
#define BK 32

__device__ __forceinline__ void gload_lds16(const void* g, void* l) {
  __builtin_amdgcn_global_load_lds(
      (const __attribute__((address_space(1))) void*)g,
      (__attribute__((address_space(3))) void*)l, 16, 0, 0);
}

// C[M,N] = act(A[M,K] @ Bt[N,K]^T + bias), bf16 in/out, fp32 accumulate.
// 1D grid with XCD-pinning raster: blocks with id%8==x all handle M-tile
// congruent to x (mod 8) -> each XCD's private L2 keeps ONE 1MB A-band hot
// across the full N sweep; B tiles are shared across XCDs via L3.
__global__ __launch_bounds__(256) void gemm_bt_bias_act(
    const u16* __restrict__ A, const u16* __restrict__ Bt,
    const float* __restrict__ bias, u16* __restrict__ C,
    int M, int N, int K, int ntiles, int act) {
  __shared__ __align__(16) u16 As[BM * BK];  // 8 KB
  __shared__ __align__(16) u16 Bs[BN * BK];  // 8 KB

  const int tid = threadIdx.x;
  const int wave = tid >> 6;
  const int lane = tid & 63;
  const int wm = wave >> 1, wn = wave & 1;   // 2x2 wave grid, 64x64 each
  const int l15 = lane & 15, quad = lane >> 4;

  // XCD-pinned raster (assumes round-robin id%8 -> XCD mapping; if the
  // mapping differs this only affects locality, not correctness)
  const int id = blockIdx.x;
  const int mt = (id & 7) + (id / (8 * ntiles)) * 8;
  const int nt = (id >> 3) % ntiles;
  const int m0 = mt * BM;
  const int n0 = nt * BN;

  f32x4 acc[4][4];
#pragma unroll
  for (int i = 0; i < 4; ++i)
#pragma unroll
    for (int j = 0; j < 4; ++j) acc[i][j] = (f32x4){0.f, 0.f, 0.f, 0.f};

  for (int k0 = 0; k0 < K; k0 += BK) {
    // stage A-tile [128x32] and Bt-tile [128x32] as 512 16B-chunks each;
    // chunk c: row = c>>2, k-offset = (c&3)*8.  LDS dest must be
    // wave-uniform base + lane*16 -> chunks are lane-contiguous per wave.
#pragma unroll
    for (int h = 0; h < 2; ++h) {
      const int c = tid + h * 256;
      const int row = c >> 2, kc = (c & 3) * 8;
      const int wbase = (wave * 64 + h * 256) * 8;  // elems
      gload_lds16(A + (size_t)(m0 + row) * K + k0 + kc, (void*)(As + wbase));
      gload_lds16(Bt + (size_t)(n0 + row) * K + k0 + kc, (void*)(Bs + wbase));
    }
    __syncthreads();

    bf16x8 af[4], bfr[4];
#pragma unroll
    for (int i = 0; i < 4; ++i)
      af[i] = *(const bf16x8*)(As + (wm * 64 + i * 16 + l15) * BK + quad * 8);
#pragma unroll
    for (int j = 0; j < 4; ++j)
      bfr[j] = *(const bf16x8*)(Bs + (wn * 64 + j * 16 + l15) * BK + quad * 8);
#pragma unroll
    for (int i = 0; i < 4; ++i)
#pragma unroll
      for (int j = 0; j < 4; ++j)
        acc[i][j] = __builtin_amdgcn_mfma_f32_16x16x32_bf16(af[i], bfr[j],
                                                            acc[i][j], 0, 0, 0);
    __syncthreads();
  }

  // epilogue: C/D layout col=lane&15, row=quad*4+reg (m89-verified)
#pragma unroll
  for (int i = 0; i < 4; ++i) {
    const int row = m0 + wm * 64 + i * 16 + quad * 4;
#pragma unroll
    for (int j = 0; j < 4; ++j) {
      const int col = n0 + wn * 64 + j * 16 + l15;
      const float bv = bias[col];
#pragma unroll
      for (int r = 0; r < 4; ++r) {
        float v = acc[i][j][r] + bv;
        if (act) v = fmaxf(v, 0.f);
        C[(size_t)(row + r) * N + col] = f2bf(v);
      }
    }
  }
}

// ---------------------------------------------------------------- head: h@W4+b4, sigmoid
__global__ __launch_bounds__(256) void head_kernel(
    const u16* __restrict__ h, const float2* __restrict__ W4,
    const float* __restrict__ b4, float* __restrict__ out, int H) {
  const int row = blockIdx.x;
  const u16* hr = h + (size_t)row * H;
  const int tid = threadIdx.x;
  float p0 = 0.f, p1 = 0.f;
#pragma unroll
  for (int ii = 0; ii < 2; ++ii) {
    const int base = tid * 16 + ii * 8;  // 8 bf16 per uint4
    const uint4 hv = *(const uint4*)(hr + base);
    const unsigned uu[4] = {hv.x, hv.y, hv.z, hv.w};
#pragma unroll
    for (int j = 0; j < 4; ++j) {
      float a0 = bf2f(uu[j] & 0xffffu);
      float a1 = bf2f(uu[j] >> 16);
      float2 w0 = W4[base + 2 * j];
      float2 w1 = W4[base + 2 * j + 1];
      p0 += a0 * w0.x + a1 * w1.x;
      p1 += a0 * w0.y + a1 * w1.y;
    }
  }
#pragma unroll
  for (int off = 32; off > 0; off >>= 1) {
    p0 += __shfl_down(p0, off, 64);
    p1 += __shfl_down(p1, off, 64);
  }
  __shared__ float r0[4], r1[4];
  const int lane = tid & 63, wave = tid >> 6;
  if (lane == 0) { r0[wave] = p0; r1[wave] = p1; }
  __syncthreads();
  if (tid == 0) {
    float l0 = r0[0] + r0[1] + r0[2] + r0[3] + b4[0];
    float l1 = r1[0] + r1[1] + r1[2] + r1[3] + b4[1];
    out[1 + row * 2] = 1.f / (1.f + __expf(-l0));
    out[2 + row * 2] = 1.f / (1.f + __expf(-l1));
  }
}

// ---------------------------------------------------------------- launch
extern "C" void kernel_launch(void* const* d_in, const int* in_sizes, int n_in,
                              void* d_out, int out_size, void* d_ws,
                              size_t ws_size, hipStream_t stream) {
  (void)in_sizes; (void)n_in; (void)out_size; (void)ws_size;
  const float* x  = (const float*)d_in[0];
  const float* dm = (const float*)d_in[1];
  const float* al = (const float*)d_in[2];
  const float* sl = (const float*)d_in[3];
  const float* sc = (const float*)d_in[4];
  const int*   nd = (const int*)d_in[5];
  const int*   nf = (const int*)d_in[6];
  const float* W1 = (const float*)d_in[7];
  const float* b1 = (const float*)d_in[8];
  const float* W2 = (const float*)d_in[9];
  const float* b2 = (const float*)d_in[10];
  const float* W3 = (const float*)d_in[11];
  const float* b3 = (const float*)d_in[12];
  const float* W4 = (const float*)d_in[13];
  const float* b4 = (const float*)d_in[14];
  float* out = (float*)d_out;

  const int B = 16384, F = 2048, H = 4096, D = 4096, K = 2048;

  // workspace layout (352 MB): xb | wt | hA | hB
  char* ws = (char*)d_ws;
  u16* xb = (u16*)ws;                                         // B*F bf16
  u16* wt = (u16*)(ws + (size_t)B * F * 2);                   // H*H bf16 (reused W1t/W2t/W3t)
  u16* hA = (u16*)(ws + (size_t)B * F * 2 + (size_t)H * H * 2);
  u16* hB = hA + (size_t)B * H;

  // loss
  init_loss_kernel<<<1, 1, 0, stream>>>(sc, nd, nf, out);
  subdom_kernel<<<1024, 256, 0, stream>>>((const float4*)dm, (const float4*)sl,
                                          (const float4*)al, out, D * K / 4,
                                          K / 4 - 1);
  // MLP
  const int NT = H / BN;                       // 32 N-tiles
  const int NB = (B / BM) * NT;                // 4096 blocks
  cast_f32_bf16_kernel<<<4096, 256, 0, stream>>>((const float4*)x, xb, B * F / 4);
  transpose_cast_kernel<<<dim3(H / 32, F / 32), dim3(32, 8), 0, stream>>>(W1, wt, F, H);
  gemm_bt_bias_act<<<NB, 256, 0, stream>>>(xb, wt, b1, hA, B, H, F, NT, 1);
  transpose_cast_kernel<<<dim3(H / 32, H / 32), dim3(32, 8), 0, stream>>>(W2, wt, H, H);
  gemm_bt_bias_act<<<NB, 256, 0, stream>>>(hA, wt, b2, hB, B, H, H, NT, 1);
  transpose_cast_kernel<<<dim3(H / 32, H / 32), dim3(32, 8), 0, stream>>>(W3, wt, H, H);
  gemm_bt_bias_act<<<NB, 256, 0, stream>>>(hB, wt, b3, hA, B, H, H, NT, 1);
  head_kernel<<<B, 256, 0, stream>>>(hA, (const float2*)W4, b4, out, H);
}

// Round 3
// 2230.457 us; speedup vs baseline: 1.0799x; 1.0799x over previous
//
#include <hip/hip_runtime.h>
#include <cstdint>
#include <cstddef>

typedef unsigned short u16;
typedef __attribute__((ext_vector_type(8))) __bf16 bf16x8;
typedef __attribute__((ext_vector_type(4))) float f32x4;

// fp32 -> bf16 round-to-nearest-even (inputs are well-behaved, no NaN path)
__device__ __forceinline__ u16 f2bf(float f) {
  union { float f; unsigned u; } v; v.f = f;
  unsigned r = v.u + 0x7FFFu + ((v.u >> 16) & 1u);
  return (u16)(r >> 16);
}
__device__ __forceinline__ float bf2f(unsigned h) {
  union { unsigned u; float f; } v; v.u = h << 16;
  return v.f;
}

// ---------------------------------------------------------------- subdom loss
__global__ void init_loss_kernel(const float* __restrict__ c,
                                 const int* __restrict__ D,
                                 const int* __restrict__ K,
                                 float* __restrict__ out) {
  out[0] = -c[0] * (float)D[0] * (float)K[0];
}

__global__ void subdom_kernel(const float4* __restrict__ dm,
                              const float4* __restrict__ sl,
                              const float4* __restrict__ alpha4,
                              float* __restrict__ out, int n4, int k4mask) {
  const int stride = gridDim.x * blockDim.x;
  float s = 0.f;
  for (int i = blockIdx.x * blockDim.x + threadIdx.x; i < n4; i += stride) {
    float4 d = dm[i], l = sl[i], a = alpha4[i & k4mask];
    s += fmaxf(fmaf(a.x, l.x - d.x, 1.f), 0.f);
    s += fmaxf(fmaf(a.y, l.y - d.y, 1.f), 0.f);
    s += fmaxf(fmaf(a.z, l.z - d.z, 1.f), 0.f);
    s += fmaxf(fmaf(a.w, l.w - d.w, 1.f), 0.f);
  }
#pragma unroll
  for (int off = 32; off > 0; off >>= 1) s += __shfl_down(s, off, 64);
  __shared__ float red[4];
  const int lane = threadIdx.x & 63, wave = threadIdx.x >> 6;
  if (lane == 0) red[wave] = s;
  __syncthreads();
  if (threadIdx.x == 0) atomicAdd(out, red[0] + red[1] + red[2] + red[3]);
}

// ---------------------------------------------------------------- casts
__global__ void cast_f32_bf16_kernel(const float4* __restrict__ in,
                                     u16* __restrict__ out, int n4) {
  const int stride = gridDim.x * blockDim.x;
  for (int i = blockIdx.x * blockDim.x + threadIdx.x; i < n4; i += stride) {
    float4 v = in[i];
    uint2 p;
    p.x = (unsigned)f2bf(v.x) | ((unsigned)f2bf(v.y) << 16);
    p.y = (unsigned)f2bf(v.z) | ((unsigned)f2bf(v.w) << 16);
    ((uint2*)out)[i] = p;
  }
}

// in: [K,N] fp32 row-major  ->  out: [N,K] bf16 row-major
__global__ void transpose_cast_kernel(const float* __restrict__ in,
                                      u16* __restrict__ out, int K, int N) {
  __shared__ float tile[32][33];
  const int bx = blockIdx.x * 32;  // N
  const int by = blockIdx.y * 32;  // K
  const int tx = threadIdx.x, ty = threadIdx.y;
#pragma unroll
  for (int i = ty; i < 32; i += 8)
    tile[i][tx] = in[(size_t)(by + i) * N + bx + tx];
  __syncthreads();
#pragma unroll
  for (int i = ty; i < 32; i += 8)
    out[(size_t)(bx + i) * K + by + tx] = f2bf(tile[tx][i]);
}

// ---------------------------------------------------------------- GEMM
// m97 structure + two changes:
//  * BK=64: 16 MFMAs per barrier (was 8) -> amortize the vmcnt(0) barrier drain
//  * XOR-swizzled k-chunk axis: LDS slot j of row r holds global k-chunk
//    j^(r&7) (swizzle applied on the GLOBAL fetch address, since
//    global_load_lds forces linear lane-contiguous LDS writes). Frag reads
//    then hit all 32 banks per 32-lane phase instead of 16.
#define BM 128
#define BN 128
#define BK 64

__device__ __forceinline__ void gload_lds16(const void* g, void* l) {
  __builtin_amdgcn_global_load_lds(
      (const __attribute__((address_space(1))) void*)g,
      (__attribute__((address_space(3))) void*)l, 16, 0, 0);
}

// C[M,N] = act(A[M,K] @ Bt[N,K]^T + bias), bf16 in/out, fp32 accumulate
__global__ __launch_bounds__(256) void gemm_bt_bias_act(
    const u16* __restrict__ A, const u16* __restrict__ Bt,
    const float* __restrict__ bias, u16* __restrict__ C,
    int M, int N, int K, int act) {
  __shared__ __align__(16) u16 As[BM * BK];  // 16 KB
  __shared__ __align__(16) u16 Bs[BN * BK];  // 16 KB

  const int tid = threadIdx.x;
  const int wave = tid >> 6;
  const int lane = tid & 63;
  const int wm = wave >> 1, wn = wave & 1;   // 2x2 wave grid, 64x64 each
  const int l15 = lane & 15, quad = lane >> 4;
  const int sw = l15 & 7;                    // row-dependent swizzle key

  const int m0 = blockIdx.y * BM;
  const int n0 = blockIdx.x * BN;

  f32x4 acc[4][4];
#pragma unroll
  for (int i = 0; i < 4; ++i)
#pragma unroll
    for (int j = 0; j < 4; ++j) acc[i][j] = (f32x4){0.f, 0.f, 0.f, 0.f};

  // staging indices (per-lane global address, wave-uniform LDS base)
  // chunk c = tid + h*256: row = c>>3, LDS slot j = c&7 holds global
  // k-chunk (j ^ (row&7)); LDS elems = c*8 (linear, lane-contiguous).
  int srow[4], skc[4];
#pragma unroll
  for (int h = 0; h < 4; ++h) {
    const int c = tid + h * 256;
    srow[h] = c >> 3;
    skc[h] = (((c & 7) ^ (srow[h] & 7)) << 3);
  }

  for (int k0 = 0; k0 < K; k0 += BK) {
#pragma unroll
    for (int h = 0; h < 4; ++h) {
      const int wbase = (h * 256 + wave * 64) * 8;  // elems
      gload_lds16(A + (size_t)(m0 + srow[h]) * K + k0 + skc[h],
                  (void*)(As + wbase));
      gload_lds16(Bt + (size_t)(n0 + srow[h]) * K + k0 + skc[h],
                  (void*)(Bs + wbase));
    }
    __syncthreads();

#pragma unroll
    for (int s = 0; s < 2; ++s) {
      bf16x8 af[4], bfr[4];
#pragma unroll
      for (int i = 0; i < 4; ++i)
        af[i] = *(const bf16x8*)(As + (wm * 64 + i * 16 + l15) * BK +
                                 ((((s << 2) + quad) ^ sw) << 3));
#pragma unroll
      for (int j = 0; j < 4; ++j)
        bfr[j] = *(const bf16x8*)(Bs + (wn * 64 + j * 16 + l15) * BK +
                                  ((((s << 2) + quad) ^ sw) << 3));
#pragma unroll
      for (int i = 0; i < 4; ++i)
#pragma unroll
        for (int j = 0; j < 4; ++j)
          acc[i][j] = __builtin_amdgcn_mfma_f32_16x16x32_bf16(
              af[i], bfr[j], acc[i][j], 0, 0, 0);
    }
    __syncthreads();
  }

  // epilogue: C/D layout col=lane&15, row=quad*4+reg (m89-verified)
#pragma unroll
  for (int i = 0; i < 4; ++i) {
    const int row = m0 + wm * 64 + i * 16 + quad * 4;
#pragma unroll
    for (int j = 0; j < 4; ++j) {
      const int col = n0 + wn * 64 + j * 16 + l15;
      const float bv = bias[col];
#pragma unroll
      for (int r = 0; r < 4; ++r) {
        float v = acc[i][j][r] + bv;
        if (act) v = fmaxf(v, 0.f);
        C[(size_t)(row + r) * N + col] = f2bf(v);
      }
    }
  }
}

// ---------------------------------------------------------------- head: h@W4+b4, sigmoid
__global__ __launch_bounds__(256) void head_kernel(
    const u16* __restrict__ h, const float2* __restrict__ W4,
    const float* __restrict__ b4, float* __restrict__ out, int H) {
  const int row = blockIdx.x;
  const u16* hr = h + (size_t)row * H;
  const int tid = threadIdx.x;
  float p0 = 0.f, p1 = 0.f;
#pragma unroll
  for (int ii = 0; ii < 2; ++ii) {
    const int base = tid * 16 + ii * 8;  // 8 bf16 per uint4
    const uint4 hv = *(const uint4*)(hr + base);
    const unsigned uu[4] = {hv.x, hv.y, hv.z, hv.w};
#pragma unroll
    for (int j = 0; j < 4; ++j) {
      float a0 = bf2f(uu[j] & 0xffffu);
      float a1 = bf2f(uu[j] >> 16);
      float2 w0 = W4[base + 2 * j];
      float2 w1 = W4[base + 2 * j + 1];
      p0 += a0 * w0.x + a1 * w1.x;
      p1 += a0 * w0.y + a1 * w1.y;
    }
  }
#pragma unroll
  for (int off = 32; off > 0; off >>= 1) {
    p0 += __shfl_down(p0, off, 64);
    p1 += __shfl_down(p1, off, 64);
  }
  __shared__ float r0[4], r1[4];
  const int lane = tid & 63, wave = tid >> 6;
  if (lane == 0) { r0[wave] = p0; r1[wave] = p1; }
  __syncthreads();
  if (tid == 0) {
    float l0 = r0[0] + r0[1] + r0[2] + r0[3] + b4[0];
    float l1 = r1[0] + r1[1] + r1[2] + r1[3] + b4[1];
    out[1 + row * 2] = 1.f / (1.f + __expf(-l0));
    out[2 + row * 2] = 1.f / (1.f + __expf(-l1));
  }
}

// ---------------------------------------------------------------- launch
extern "C" void kernel_launch(void* const* d_in, const int* in_sizes, int n_in,
                              void* d_out, int out_size, void* d_ws,
                              size_t ws_size, hipStream_t stream) {
  (void)in_sizes; (void)n_in; (void)out_size; (void)ws_size;
  const float* x  = (const float*)d_in[0];
  const float* dm = (const float*)d_in[1];
  const float* al = (const float*)d_in[2];
  const float* sl = (const float*)d_in[3];
  const float* sc = (const float*)d_in[4];
  const int*   nd = (const int*)d_in[5];
  const int*   nf = (const int*)d_in[6];
  const float* W1 = (const float*)d_in[7];
  const float* b1 = (const float*)d_in[8];
  const float* W2 = (const float*)d_in[9];
  const float* b2 = (const float*)d_in[10];
  const float* W3 = (const float*)d_in[11];
  const float* b3 = (const float*)d_in[12];
  const float* W4 = (const float*)d_in[13];
  const float* b4 = (const float*)d_in[14];
  float* out = (float*)d_out;

  const int B = 16384, F = 2048, H = 4096, D = 4096, K = 2048;

  // workspace layout (352 MB): xb | wt | hA | hB
  char* ws = (char*)d_ws;
  u16* xb = (u16*)ws;                                         // B*F bf16
  u16* wt = (u16*)(ws + (size_t)B * F * 2);                   // H*H bf16 (reused W1t/W2t/W3t)
  u16* hA = (u16*)(ws + (size_t)B * F * 2 + (size_t)H * H * 2);
  u16* hB = hA + (size_t)B * H;

  // loss
  init_loss_kernel<<<1, 1, 0, stream>>>(sc, nd, nf, out);
  subdom_kernel<<<1024, 256, 0, stream>>>((const float4*)dm, (const float4*)sl,
                                          (const float4*)al, out, D * K / 4,
                                          K / 4 - 1);
  // MLP
  cast_f32_bf16_kernel<<<4096, 256, 0, stream>>>((const float4*)x, xb, B * F / 4);
  transpose_cast_kernel<<<dim3(H / 32, F / 32), dim3(32, 8), 0, stream>>>(W1, wt, F, H);
  gemm_bt_bias_act<<<dim3(H / BN, B / BM), 256, 0, stream>>>(xb, wt, b1, hA, B, H, F, 1);
  transpose_cast_kernel<<<dim3(H / 32, H / 32), dim3(32, 8), 0, stream>>>(W2, wt, H, H);
  gemm_bt_bias_act<<<dim3(H / BN, B / BM), 256, 0, stream>>>(hA, wt, b2, hB, B, H, H, 1);
  transpose_cast_kernel<<<dim3(H / 32, H / 32), dim3(32, 8), 0, stream>>>(W3, wt, H, H);
  gemm_bt_bias_act<<<dim3(H / BN, B / BM), 256, 0, stream>>>(hB, wt, b3, hA, B, H, H, 1);
  head_kernel<<<B, 256, 0, stream>>>(hA, (const float2*)W4, b4, out, H);
}